// Round 1
// baseline (448.425 us; speedup 1.0000x reference)
//
#include <hip/hip_runtime.h>
#include <hip/hip_bf16.h>
#include <math.h>

typedef __attribute__((ext_vector_type(8))) short short8;
typedef __attribute__((ext_vector_type(4))) float f32x4;

#define VOCAB 8192
#define NSAMP 8192
#define INTER 4352
#define EMB   512

__device__ __forceinline__ float gelu_exact(float x) {
    return 0.5f * x * (1.0f + erff(x * 0.70710678118654752f));
}
__device__ __forceinline__ unsigned short f2bf(float x) {
    __hip_bfloat16 b = __float2bfloat16(x);
    return *reinterpret_cast<unsigned short*>(&b);
}

// ---------------- histogram ----------------
__global__ void k_zero_cnt(int* cnt) {
    cnt[blockIdx.x * 256 + threadIdx.x] = 0;
}
__global__ void k_hist(const int* __restrict__ xt, int* __restrict__ cnt) {
    int n = blockIdx.x * 256 + threadIdx.x;
    atomicAdd(&cnt[xt[n]], 1);
}

// ---------------- BN1 stats (cnt-weighted over W1 rows) ----------------
// grid (68 channel-blocks, 8 v-chunks); block handles 64 channels x 1024 v
__global__ __launch_bounds__(256) void k_stats1p(const float* __restrict__ W1,
                                                 const int* __restrict__ cnt,
                                                 float* __restrict__ ps1,
                                                 float* __restrict__ ps2) {
    const int i0 = blockIdx.x * 64;
    const int v0 = blockIdx.y * 1024;
    const int t = threadIdx.x;
    const int c = t >> 2;           // channel within block
    const int vl = (t & 3) * 4;     // v offset within 16-wide group
    const float* wrow = W1 + (size_t)(i0 + c) * VOCAB + v0;
    const int* crow = cnt + v0;
    float s1 = 0.f, s2 = 0.f;
    for (int it = 0; it < 64; ++it) {
        int v = vl + it * 16;
        float4 w = *(const float4*)(wrow + v);
        int4 cn = *(const int4*)(crow + v);
        s1 += cn.x * w.x + cn.y * w.y + cn.z * w.z + cn.w * w.w;
        s2 += cn.x * w.x * w.x + cn.y * w.y * w.y + cn.z * w.z * w.z + cn.w * w.w * w.w;
    }
    s1 += __shfl_xor(s1, 1); s1 += __shfl_xor(s1, 2);
    s2 += __shfl_xor(s2, 1); s2 += __shfl_xor(s2, 2);
    if ((t & 3) == 0) {
        ps1[blockIdx.y * INTER + i0 + c] = s1;
        ps2[blockIdx.y * INTER + i0 + c] = s2;
    }
}

__global__ void k_stats1f(const float* __restrict__ ps1, const float* __restrict__ ps2,
                          const float* __restrict__ g1, float* __restrict__ a1,
                          float* __restrict__ m1) {
    int i = blockIdx.x * 256 + threadIdx.x;   // 17*256 == 4352 exactly
    float s1 = 0.f, s2 = 0.f;
    for (int j = 0; j < 8; ++j) { s1 += ps1[j * INTER + i]; s2 += ps2[j * INTER + i]; }
    float m = s1 * (1.f / NSAMP);
    float var = s2 * (1.f / NSAMP) - m * m;
    a1[i] = g1[i] * rsqrtf(var + 1e-5f);
    m1[i] = m;
}

// ---------------- build Hact[v, i] (bf16) = gelu(a1*(W1[i,v]-m1)+beta1) ----------------
// grid (68 channel-blocks, 32 v-chunks); block: 64 channels x 256 v, LDS transpose
__global__ __launch_bounds__(256) void k_build(const float* __restrict__ W1,
                                               const float* __restrict__ a1,
                                               const float* __restrict__ m1,
                                               const float* __restrict__ beta1,
                                               unsigned short* __restrict__ Hact) {
    __shared__ __align__(16) unsigned short ldsT[256 * 64];   // [vv][c]
    const int i0 = blockIdx.x * 64;
    const int v0 = blockIdx.y * 256;
    const int t = threadIdx.x;
    const int c = t >> 2;
    const int vl = (t & 3) * 4;
    const float a = a1[i0 + c], m = m1[i0 + c], be = beta1[i0 + c];
    const float* wrow = W1 + (size_t)(i0 + c) * VOCAB + v0;
    #pragma unroll
    for (int it = 0; it < 16; ++it) {
        int vv = vl + it * 16;
        float4 w = *(const float4*)(wrow + vv);
        ldsT[(vv + 0) * 64 + c] = f2bf(gelu_exact(a * (w.x - m) + be));
        ldsT[(vv + 1) * 64 + c] = f2bf(gelu_exact(a * (w.y - m) + be));
        ldsT[(vv + 2) * 64 + c] = f2bf(gelu_exact(a * (w.z - m) + be));
        ldsT[(vv + 3) * 64 + c] = f2bf(gelu_exact(a * (w.w - m) + be));
    }
    __syncthreads();
    #pragma unroll
    for (int p = 0; p < 16; ++p) {
        int vv = p * 16 + (t >> 4);
        int ii = (t & 15) * 4;
        *(ushort4*)&Hact[(size_t)(v0 + vv) * INTER + i0 + ii] = *(ushort4*)&ldsT[vv * 64 + ii];
    }
}

// ---------------- W2 fp32 -> bf16 ----------------
__global__ void k_w2bf(const float* __restrict__ W2, unsigned short* __restrict__ W2b) {
    int idx = (blockIdx.x * 256 + threadIdx.x) * 4;
    float4 w = *(const float4*)(W2 + idx);
    ushort4 u;
    u.x = f2bf(w.x); u.y = f2bf(w.y); u.z = f2bf(w.z); u.w = f2bf(w.w);
    *(ushort4*)(W2b + idx) = u;
}

// ---------------- GEMM: C[8192,512] = A[8192,4352] * B[512,4352]^T (bf16 MFMA) ----------
__global__ __launch_bounds__(256) void k_gemm(const unsigned short* __restrict__ A,
                                              const unsigned short* __restrict__ B,
                                              float* __restrict__ C) {
    __shared__ __align__(16) unsigned short sA[128 * 64];
    __shared__ __align__(16) unsigned short sB[128 * 64];
    const int m0 = blockIdx.x * 128;
    const int n0 = blockIdx.y * 128;
    const int t = threadIdx.x;
    const int lane = t & 63;
    const int wave = t >> 6;
    const int wr = wave >> 1, wc = wave & 1;     // 2x2 waves, each 64x64
    const int mq = lane & 15, kq = lane >> 4;
    f32x4 acc[4][4];
    #pragma unroll
    for (int r = 0; r < 4; ++r)
        #pragma unroll
        for (int c = 0; c < 4; ++c) acc[r][c] = (f32x4){0.f, 0.f, 0.f, 0.f};
    const int tr = t >> 3;          // 0..31
    const int tk = (t & 7) * 8;     // 0..56
    for (int k0 = 0; k0 < INTER; k0 += 64) {
        #pragma unroll
        for (int p = 0; p < 4; ++p) {
            int row = p * 32 + tr;
            *(short8*)&sA[row * 64 + tk] = *(const short8*)(A + (size_t)(m0 + row) * INTER + k0 + tk);
            *(short8*)&sB[row * 64 + tk] = *(const short8*)(B + (size_t)(n0 + row) * INTER + k0 + tk);
        }
        __syncthreads();
        #pragma unroll
        for (int kk = 0; kk < 64; kk += 32) {
            short8 af[4], bf[4];
            #pragma unroll
            for (int r = 0; r < 4; ++r)
                af[r] = *(const short8*)&sA[(wr * 64 + r * 16 + mq) * 64 + kk + kq * 8];
            #pragma unroll
            for (int c = 0; c < 4; ++c)
                bf[c] = *(const short8*)&sB[(wc * 64 + c * 16 + mq) * 64 + kk + kq * 8];
            #pragma unroll
            for (int r = 0; r < 4; ++r)
                #pragma unroll
                for (int c = 0; c < 4; ++c)
                    acc[r][c] = __builtin_amdgcn_mfma_f32_16x16x32_bf16(af[r], bf[c], acc[r][c], 0, 0, 0);
        }
        __syncthreads();
    }
    #pragma unroll
    for (int r = 0; r < 4; ++r) {
        #pragma unroll
        for (int c = 0; c < 4; ++c) {
            int col = n0 + wc * 64 + c * 16 + mq;
            int rowb = m0 + wr * 64 + r * 16 + kq * 4;
            #pragma unroll
            for (int j = 0; j < 4; ++j)
                C[(size_t)(rowb + j) * EMB + col] = acc[r][c][j];
        }
    }
}

// ---------------- BN2 stats (cnt-weighted column stats of h2raw) ----------------
__global__ __launch_bounds__(256) void k_stats2p(const float* __restrict__ h2,
                                                 const int* __restrict__ cnt,
                                                 float* __restrict__ ps1,
                                                 float* __restrict__ ps2) {
    const int v0 = blockIdx.x * 256;
    const int t = threadIdx.x;
    const int e = t * 2;
    float s1a = 0.f, s1b = 0.f, s2a = 0.f, s2b = 0.f;
    for (int v = 0; v < 256; ++v) {
        int cw = cnt[v0 + v];
        if (cw == 0) continue;   // wave-uniform branch
        float w = (float)cw;
        float2 h = *(const float2*)(h2 + (size_t)(v0 + v) * EMB + e);
        s1a += w * h.x; s1b += w * h.y;
        s2a += w * h.x * h.x; s2b += w * h.y * h.y;
    }
    float2 o1 = {s1a, s1b}, o2 = {s2a, s2b};
    *(float2*)(ps1 + blockIdx.x * EMB + e) = o1;
    *(float2*)(ps2 + blockIdx.x * EMB + e) = o2;
}

__global__ void k_stats2f(const float* __restrict__ ps1, const float* __restrict__ ps2,
                          const float* __restrict__ g2, float* __restrict__ a2,
                          float* __restrict__ m2) {
    int e = blockIdx.x * 256 + threadIdx.x;   // 2*256 == 512
    float s1 = 0.f, s2 = 0.f;
    for (int j = 0; j < 32; ++j) { s1 += ps1[j * EMB + e]; s2 += ps2[j * EMB + e]; }
    float m = s1 * (1.f / NSAMP);
    float var = s2 * (1.f / NSAMP) - m * m;
    a2[e] = g2[e] * rsqrtf(var + 1e-5f);
    m2[e] = m;
}

// ---------------- final gather + BN2 + gelu ----------------
__global__ __launch_bounds__(256) void k_final(const float* __restrict__ h2,
                                               const int* __restrict__ xt,
                                               const float* __restrict__ a2,
                                               const float* __restrict__ m2,
                                               const float* __restrict__ beta2,
                                               float* __restrict__ out) {
    const int t = threadIdx.x;
    const int n = blockIdx.x * 2 + (t >> 7);
    const int e = (t & 127) * 4;
    const int v = xt[n];
    float4 h = *(const float4*)(h2 + (size_t)v * EMB + e);
    float4 a = *(const float4*)(a2 + e);
    float4 m = *(const float4*)(m2 + e);
    float4 b = *(const float4*)(beta2 + e);
    float4 o;
    o.x = gelu_exact(a.x * (h.x - m.x) + b.x);
    o.y = gelu_exact(a.y * (h.y - m.y) + b.y);
    o.z = gelu_exact(a.z * (h.z - m.z) + b.z);
    o.w = gelu_exact(a.w * (h.w - m.w) + b.w);
    *(float4*)(out + (size_t)n * EMB + e) = o;
}

extern "C" void kernel_launch(void* const* d_in, const int* in_sizes, int n_in,
                              void* d_out, int out_size, void* d_ws, size_t ws_size,
                              hipStream_t stream) {
    const int* xt      = (const int*)d_in[0];
    const float* W1    = (const float*)d_in[1];
    // d_in[2] = b1 (cancels in BN), d_in[3] = g1, d_in[4] = beta1
    const float* g1    = (const float*)d_in[3];
    const float* beta1 = (const float*)d_in[4];
    const float* W2    = (const float*)d_in[5];
    // d_in[6] = b2 (cancels in BN)
    const float* g2    = (const float*)d_in[7];
    const float* beta2 = (const float*)d_in[8];
    float* out = (float*)d_out;

    char* ws = (char*)d_ws;
    int*   cnt  = (int*)  (ws + 0);          // 32 KB
    float* a1   = (float*)(ws + 32768);      // 17 KB
    float* m1   = (float*)(ws + 50176);      // 17 KB
    float* ps1  = (float*)(ws + 67584);      // 8*4352*4
    float* ps2  = (float*)(ws + 206848);     // 8*4352*4
    float* a2   = (float*)(ws + 346112);     // 2 KB
    float* m2   = (float*)(ws + 348160);     // 2 KB
    float* ps1b = (float*)(ws + 350208);     // 32*512*4
    float* ps2b = (float*)(ws + 415744);     // 32*512*4
    unsigned short* W2b  = (unsigned short*)(ws + 481280);    // 4.25 MB
    unsigned short* Hact = (unsigned short*)(ws + 4937728);   // 71.3 MB
    float* h2   = (float*)(ws + 76240896);   // 16.8 MB  (total ~93 MB)

    k_zero_cnt<<<32, 256, 0, stream>>>(cnt);
    k_hist<<<32, 256, 0, stream>>>(xt, cnt);
    k_stats1p<<<dim3(68, 8), 256, 0, stream>>>(W1, cnt, ps1, ps2);
    k_stats1f<<<17, 256, 0, stream>>>(ps1, ps2, g1, a1, m1);
    k_build<<<dim3(68, 32), 256, 0, stream>>>(W1, a1, m1, beta1, Hact);
    k_w2bf<<<2176, 256, 0, stream>>>(W2, W2b);
    k_gemm<<<dim3(64, 4), 256, 0, stream>>>(Hact, W2b, h2);
    k_stats2p<<<32, 256, 0, stream>>>(h2, cnt, ps1b, ps2b);
    k_stats2f<<<2, 256, 0, stream>>>(ps1b, ps2b, g2, a2, m2);
    k_final<<<4096, 256, 0, stream>>>(h2, xt, a2, m2, beta2, out);
}